// Round 8
// baseline (71.016 us; speedup 1.0000x reference)
//
#include <hip/hip_runtime.h>

// PositionLossVal: offset [4,18,512,512] f32, optical_flow [4,8,512,512] f32 -> scalar f32.
// Per pixel: x=off[i], y=off[i+9] (i<9); u=flow[j], v=flow[j+1] (j<4).
// md = inside ? perp : min(d1,d2); min over j, mean over i, sum over b,h,w, /(h*w).
// min over j in squared domain -> 1 sqrt per (pixel,i).
// inside: x0*(x0-u)<=0, x0 = u*(x^2+v*y)/uu  <=>  w*(w-uu)<=0 with w = x^2+v*y.
//
// Ledger: R5 fused same-address atomic tail +60us. R1/R4/R7: PPT=4 => 180 VGPR
// (2 waves/SIMD) or 1.1KB/thread spill under a cap — dead. R2/R3/R6 (PPT<=2,
// 64-or-so VGPR) plateau ~27us: VALUBusy ~33% == pure-VALU 7.3us over 22us wall,
// rest = exposed load latency at ~2.8 effective waves/SIMD.
// R8: PPT=1, ALL 23 loads issued up-front, __launch_bounds__(256,8) => <=64 VGPR
// by construction (live set ~50) => 8 waves/SIMD AND ~23 outstanding dwords/lane.
// Spill tripwire: WRITE_SIZE must stay ~0.

#define HW_BITS 18
#define HW_ (1 << HW_BITS)          // 512*512
#define NOFF 9
#define NFLOW 4
#define NPIX (4 * HW_)              // 1,048,576 pixels, one thread each
#define BLK 256
#define GRID1 (NPIX / BLK)          // 4096 blocks
#define NPART (GRID1 * (BLK / 64))  // 16384 wave partials (64 KB)
#define RBLK 1024

__global__ __launch_bounds__(BLK, 8)   // min 8 waves/EU => allocator targets <=64 VGPR
void pos_loss_main(const float* __restrict__ off, const float* __restrict__ flow,
                   float* __restrict__ partial)
{
    const int g  = blockIdx.x * BLK + threadIdx.x;   // pixel id
    const int b  = g >> HW_BITS;
    const int hw = g & (HW_ - 1);
    const float* offb = off  + ((size_t)b * (2 * NOFF)) * HW_ + hw;
    const float* flb  = flow + ((size_t)b * 8) * HW_ + hw;

    // Issue ALL 23 dword loads before any use: 23 outstanding per lane, progressive
    // vmcnt drain. Fits 64 VGPR at PPT=1 (this is the whole point of this round).
    float f[NFLOW + 1];
#pragma unroll
    for (int j = 0; j <= NFLOW; ++j) f[j] = flb[(size_t)j * HW_];
    float xs[NOFF], ys[NOFF];
#pragma unroll
    for (int i = 0; i < NOFF; ++i) {
        xs[i] = offb[(size_t)i * HW_];
        ys[i] = offb[(size_t)(i + NOFF) * HW_];
    }

    // Per-j invariants: uu = u^2+v^2, r = 1/uu  (8 regs).
    float uu_[NFLOW], r_[NFLOW];
#pragma unroll
    for (int j = 0; j < NFLOW; ++j) {
        const float u = f[j], v = f[j + 1];
        const float uu = fmaf(u, u, v * v);
        uu_[j] = uu;
        r_[j]  = __builtin_amdgcn_rcpf(uu);
    }

    float acc = 0.f;
#pragma unroll
    for (int i = 0; i < NOFF; ++i) {
        const float x  = xs[i], y = ys[i];
        const float x2 = x * x;
        const float d1sq = fmaf(y, y, x2);
        float m2 = 1e30f;
#pragma unroll
        for (int j = 0; j < NFLOW; ++j) {
            const float u = f[j], v = f[j + 1];
            const float w   = fmaf(v, y, x2);                 // x^2 + v*y
            const float ins = w * (w - uu_[j]);               // sign == x0*(x0-u)
            const float tt  = fmaf(v, x, -(u * y));           // v*x - u*y
            const float p2  = (tt * tt) * r_[j];
            const float dx = x - u, dy = y - v;
            const float d2sq = fmaf(dy, dy, dx * dx);
            const float e2  = fminf(d1sq, d2sq);
            const float md2 = (ins <= 0.f) ? p2 : e2;
            m2 = fminf(m2, md2);
        }
        acc += __builtin_amdgcn_sqrtf(m2);
    }

    // Per-wave shuffle reduce; no __syncthreads, no LDS — waves retire independently.
#pragma unroll
    for (int o = 32; o > 0; o >>= 1) acc += __shfl_down(acc, o, 64);
    if ((threadIdx.x & 63) == 0)
        partial[blockIdx.x * (BLK / 64) + (threadIdx.x >> 6)] = acc;
}

__global__ __launch_bounds__(RBLK)
void pos_loss_reduce(const float* __restrict__ partial, float* __restrict__ out)
{
    float s = 0.f;
#pragma unroll
    for (int k = 0; k < NPART / RBLK; ++k)          // 16 coalesced loads
        s += partial[k * RBLK + (int)threadIdx.x];
#pragma unroll
    for (int o = 32; o > 0; o >>= 1) s += __shfl_down(s, o, 64);
    __shared__ float sm[RBLK / 64];                 // 16 wave sums
    const int lane = threadIdx.x & 63, wid = threadIdx.x >> 6;
    if (lane == 0) sm[wid] = s;
    __syncthreads();
    if (wid == 0) {
        float v = (lane < RBLK / 64) ? sm[lane] : 0.f;
#pragma unroll
        for (int o = 8; o > 0; o >>= 1) v += __shfl_down(v, o, 64);
        if (lane == 0)
            out[0] = v * (1.0f / (9.0f * (float)HW_));
    }
}

extern "C" void kernel_launch(void* const* d_in, const int* in_sizes, int n_in,
                              void* d_out, int out_size, void* d_ws, size_t ws_size,
                              hipStream_t stream) {
    const float* offset = (const float*)d_in[0];   // [4,18,512,512]
    const float* flow   = (const float*)d_in[1];   // [4,8,512,512]
    float* partial = (float*)d_ws;                 // NPART floats (64 KB), fully rewritten
    float* out     = (float*)d_out;                // 1 float

    pos_loss_main<<<GRID1, BLK, 0, stream>>>(offset, flow, partial);
    pos_loss_reduce<<<1, RBLK, 0, stream>>>(partial, out);
}

// Round 9
// 56.066 us; speedup vs baseline: 1.2667x; 1.2667x over previous
//
#include <hip/hip_runtime.h>

// PositionLossVal: offset [4,18,512,512] f32, optical_flow [4,8,512,512] f32 -> scalar f32.
// Per pixel: x=off[i], y=off[i+9] (i<9); u=flow[j], v=flow[j+1] (j<4).
// md = inside ? perp : min(d1,d2); min over j, mean over i, sum over b,h,w, /(h*w).
// min over j in squared domain -> 1 sqrt per (pixel,i).
// inside: x0*(x0-u)<=0, x0 = u*(x^2+v*y)/uu  <=>  w*(w-uu)<=0 with w = x^2+v*y.
//
// Ledger: R5 same-address atomic tail +60us. PPT=4 => 180 VGPR or spill (R1/R4/R7).
// R8 (256,8) => 32-VGPR allocation, 160MB scratch spill, 83us. PPT<=2 VGPR-held
// loads plateau at ~22us main: can't have residency AND bytes-in-flight in VGPRs.
// R9: decouple via global_load_lds — 256-px x 23-ch tile (23.5KB LDS) staged by
// direct-to-LDS DMA (one width-16 instr per channel), ~23KB outstanding per block
// at zero VGPR cost; 6 blocks/CU (LDS-bound), each thread computes 1 px from LDS.

#define HW_BITS 18
#define HW_ (1 << HW_BITS)          // 512*512
#define NOFF 9
#define NFLOW 4
#define NPIX (4 * HW_)              // 1,048,576 pixels
#define NCH 23                      // 18 offset + 5 flow channels per tile
#define TPX 256                     // tile width in pixels (1KB per channel row)
#define BLK 256
#define GRID1 (NPIX / TPX)          // 4096 tiles == blocks
#define NPART (GRID1 * (BLK / 64))  // 16384 wave partials (64 KB)
#define RBLK 1024

// Direct global->LDS DMA, 16B per lane: LDS dest = wave-uniform base + lane*16,
// global src per-lane. Size must be a literal (4/12/16).
#define GLD16(g, l) __builtin_amdgcn_global_load_lds(                      \
    (const __attribute__((address_space(1))) void*)(g),                    \
    (__attribute__((address_space(3))) void*)(l), 16, 0, 0)

__global__ __launch_bounds__(BLK, 6)   // 24 waves/CU target (VGPR cap ~85; body ~50)
void pos_loss_main(const float* __restrict__ off, const float* __restrict__ flow,
                   float* __restrict__ partial)
{
    __shared__ float tile[NCH][TPX];   // 23.5 KB -> 6 blocks/CU

    const int tid  = threadIdx.x;
    const int lane = tid & 63, wid = tid >> 6;
    const int px0  = blockIdx.x * TPX;           // tile's first pixel (256 | HW_)
    const int b    = px0 >> HW_BITS;
    const int hw   = px0 & (HW_ - 1);

    const float* offb = off  + ((size_t)b * (2 * NOFF)) * HW_ + hw;
    const float* flb  = flow + ((size_t)b * 8) * HW_ + hw;

    // Stage all 23 channels; wave w takes channels w, w+4, ... (6,6,6,5 split).
    // One instruction moves a whole 1KB channel row: lane l -> tile[c][l*4..l*4+3].
    for (int c = wid; c < NCH; c += BLK / 64) {
        const float* src = (c < 2 * NOFF) ? (offb + (size_t)c * HW_)
                                          : (flb + (size_t)(c - 2 * NOFF) * HW_);
        GLD16(src + lane * 4, &tile[c][0]);
    }
    __syncthreads();   // compiler emits s_waitcnt vmcnt(0) before s_barrier: DMA drained

    // Each thread computes one pixel entirely from LDS (consecutive lanes ->
    // consecutive addresses: conflict-free).
    float f[NFLOW + 1];
#pragma unroll
    for (int j = 0; j <= NFLOW; ++j) f[j] = tile[2 * NOFF + j][tid];
    float uu_[NFLOW], r_[NFLOW];
#pragma unroll
    for (int j = 0; j < NFLOW; ++j) {
        const float u = f[j], v = f[j + 1];
        const float uu = fmaf(u, u, v * v);
        uu_[j] = uu;
        r_[j]  = __builtin_amdgcn_rcpf(uu);
    }

    float acc = 0.f;
#pragma unroll
    for (int i = 0; i < NOFF; ++i) {
        const float x  = tile[i][tid];
        const float y  = tile[i + NOFF][tid];
        const float x2 = x * x;
        const float d1sq = fmaf(y, y, x2);
        float m2 = 1e30f;
#pragma unroll
        for (int j = 0; j < NFLOW; ++j) {
            const float u = f[j], v = f[j + 1];
            const float w   = fmaf(v, y, x2);                 // x^2 + v*y
            const float ins = w * (w - uu_[j]);               // sign == x0*(x0-u)
            const float tt  = fmaf(v, x, -(u * y));           // v*x - u*y
            const float p2  = (tt * tt) * r_[j];
            const float dx = x - u, dy = y - v;
            const float d2sq = fmaf(dy, dy, dx * dx);
            const float e2  = fminf(d1sq, d2sq);
            const float md2 = (ins <= 0.f) ? p2 : e2;
            m2 = fminf(m2, md2);
        }
        acc += __builtin_amdgcn_sqrtf(m2);
    }

    // Per-wave shuffle reduce -> one partial per wave (no extra barrier).
#pragma unroll
    for (int o = 32; o > 0; o >>= 1) acc += __shfl_down(acc, o, 64);
    if (lane == 0)
        partial[blockIdx.x * (BLK / 64) + wid] = acc;
}

__global__ __launch_bounds__(RBLK)
void pos_loss_reduce(const float* __restrict__ partial, float* __restrict__ out)
{
    float s = 0.f;
#pragma unroll
    for (int k = 0; k < NPART / RBLK; ++k)          // 16 coalesced loads
        s += partial[k * RBLK + (int)threadIdx.x];
#pragma unroll
    for (int o = 32; o > 0; o >>= 1) s += __shfl_down(s, o, 64);
    __shared__ float sm[RBLK / 64];                 // 16 wave sums
    const int lane = threadIdx.x & 63, wid = threadIdx.x >> 6;
    if (lane == 0) sm[wid] = s;
    __syncthreads();
    if (wid == 0) {
        float v = (lane < RBLK / 64) ? sm[lane] : 0.f;
#pragma unroll
        for (int o = 8; o > 0; o >>= 1) v += __shfl_down(v, o, 64);
        if (lane == 0)
            out[0] = v * (1.0f / (9.0f * (float)HW_));
    }
}

extern "C" void kernel_launch(void* const* d_in, const int* in_sizes, int n_in,
                              void* d_out, int out_size, void* d_ws, size_t ws_size,
                              hipStream_t stream) {
    const float* offset = (const float*)d_in[0];   // [4,18,512,512]
    const float* flow   = (const float*)d_in[1];   // [4,8,512,512]
    float* partial = (float*)d_ws;                 // NPART floats (64 KB), fully rewritten
    float* out     = (float*)d_out;                // 1 float

    pos_loss_main<<<GRID1, BLK, 0, stream>>>(offset, flow, partial);
    pos_loss_reduce<<<1, RBLK, 0, stream>>>(partial, out);
}

// Round 10
// 33.274 us; speedup vs baseline: 2.1343x; 1.6850x over previous
//
#include <hip/hip_runtime.h>

// PositionLossVal: offset [4,18,512,512] f32, optical_flow [4,8,512,512] f32 -> scalar f32.
// Per pixel: x=off[i], y=off[i+9] (i<9); u=flow[j], v=flow[j+1] (j<4).
// md = inside ? perp : min(d1,d2); min over j, mean over i, sum over b,h,w, /(h*w).
// min over j in squared domain -> 1 sqrt per (pixel,i).
// inside: x0*(x0-u)<=0, x0 = u*(x^2+v*y)/uu  <=>  w*(w-uu)<=0 with w = x^2+v*y.
//
// Ledger: R5 same-address atomic tail +60us. PPT=4 uncapped => 180 VGPR, 2 waves/SIMD.
// TOOLCHAIN FINDING (R4/R8/R9): __launch_bounds__(256,N) makes hipcc allocate
// (512/N)/2 VGPRs — DOUBLE the declared occupancy — force-spilling any body that
// doesn't fit half the cap: (256,4)->64, (256,8)->32, (256,6)->40, each with
// 100-160MB scratch traffic. NEVER pass the min-waves arg on this toolchain.
// R10 = R9's global_load_lds tile structure, uncapped: body ~50 VGPR naturally,
// occupancy binds on LDS (23.5KB -> 6 blocks/CU), ~23KB/block in flight via DMA.

#define HW_BITS 18
#define HW_ (1 << HW_BITS)          // 512*512
#define NOFF 9
#define NFLOW 4
#define NPIX (4 * HW_)              // 1,048,576 pixels
#define NCH 23                      // 18 offset + 5 flow channels per tile
#define TPX 256                     // tile width in pixels (1KB per channel row)
#define BLK 256
#define GRID1 (NPIX / TPX)          // 4096 tiles == blocks
#define NPART (GRID1 * (BLK / 64))  // 16384 wave partials (64 KB)
#define RBLK 1024

// Direct global->LDS DMA, 16B per lane: LDS dest = wave-uniform base + lane*16,
// global src per-lane. Size must be a literal (4/12/16).
#define GLD16(g, l) __builtin_amdgcn_global_load_lds(                      \
    (const __attribute__((address_space(1))) void*)(g),                    \
    (__attribute__((address_space(3))) void*)(l), 16, 0, 0)

__global__ __launch_bounds__(BLK)   // block size only — min-waves arg is poison (see ledger)
void pos_loss_main(const float* __restrict__ off, const float* __restrict__ flow,
                   float* __restrict__ partial)
{
    __shared__ float tile[NCH][TPX];   // 23.5 KB -> 6 blocks/CU (LDS-bound occupancy)

    const int tid  = threadIdx.x;
    const int lane = tid & 63, wid = tid >> 6;
    const int px0  = blockIdx.x * TPX;           // tile's first pixel (256 | HW_)
    const int b    = px0 >> HW_BITS;
    const int hw   = px0 & (HW_ - 1);

    const float* offb = off  + ((size_t)b * (2 * NOFF)) * HW_ + hw;
    const float* flb  = flow + ((size_t)b * 8) * HW_ + hw;

    // Stage all 23 channels; wave w takes channels w, w+4, ... (6,6,6,5 split).
    // One instruction moves a whole 1KB channel row: lane l -> tile[c][l*4..l*4+3].
    for (int c = wid; c < NCH; c += BLK / 64) {
        const float* src = (c < 2 * NOFF) ? (offb + (size_t)c * HW_)
                                          : (flb + (size_t)(c - 2 * NOFF) * HW_);
        GLD16(src + lane * 4, &tile[c][0]);
    }
    __syncthreads();   // compiler drains vmcnt before s_barrier: DMA complete

    // Each thread computes one pixel entirely from LDS (consecutive lanes ->
    // consecutive addresses: conflict-free).
    float f[NFLOW + 1];
#pragma unroll
    for (int j = 0; j <= NFLOW; ++j) f[j] = tile[2 * NOFF + j][tid];
    float uu_[NFLOW], r_[NFLOW];
#pragma unroll
    for (int j = 0; j < NFLOW; ++j) {
        const float u = f[j], v = f[j + 1];
        const float uu = fmaf(u, u, v * v);
        uu_[j] = uu;
        r_[j]  = __builtin_amdgcn_rcpf(uu);
    }

    float acc = 0.f;
#pragma unroll
    for (int i = 0; i < NOFF; ++i) {
        const float x  = tile[i][tid];
        const float y  = tile[i + NOFF][tid];
        const float x2 = x * x;
        const float d1sq = fmaf(y, y, x2);
        float m2 = 1e30f;
#pragma unroll
        for (int j = 0; j < NFLOW; ++j) {
            const float u = f[j], v = f[j + 1];
            const float w   = fmaf(v, y, x2);                 // x^2 + v*y
            const float ins = w * (w - uu_[j]);               // sign == x0*(x0-u)
            const float tt  = fmaf(v, x, -(u * y));           // v*x - u*y
            const float p2  = (tt * tt) * r_[j];
            const float dx = x - u, dy = y - v;
            const float d2sq = fmaf(dy, dy, dx * dx);
            const float e2  = fminf(d1sq, d2sq);
            const float md2 = (ins <= 0.f) ? p2 : e2;
            m2 = fminf(m2, md2);
        }
        acc += __builtin_amdgcn_sqrtf(m2);
    }

    // Per-wave shuffle reduce -> one partial per wave (no extra barrier).
#pragma unroll
    for (int o = 32; o > 0; o >>= 1) acc += __shfl_down(acc, o, 64);
    if (lane == 0)
        partial[blockIdx.x * (BLK / 64) + wid] = acc;
}

__global__ __launch_bounds__(RBLK)
void pos_loss_reduce(const float* __restrict__ partial, float* __restrict__ out)
{
    float s = 0.f;
#pragma unroll
    for (int k = 0; k < NPART / RBLK; ++k)          // 16 coalesced loads
        s += partial[k * RBLK + (int)threadIdx.x];
#pragma unroll
    for (int o = 32; o > 0; o >>= 1) s += __shfl_down(s, o, 64);
    __shared__ float sm[RBLK / 64];                 // 16 wave sums
    const int lane = threadIdx.x & 63, wid = threadIdx.x >> 6;
    if (lane == 0) sm[wid] = s;
    __syncthreads();
    if (wid == 0) {
        float v = (lane < RBLK / 64) ? sm[lane] : 0.f;
#pragma unroll
        for (int o = 8; o > 0; o >>= 1) v += __shfl_down(v, o, 64);
        if (lane == 0)
            out[0] = v * (1.0f / (9.0f * (float)HW_));
    }
}

extern "C" void kernel_launch(void* const* d_in, const int* in_sizes, int n_in,
                              void* d_out, int out_size, void* d_ws, size_t ws_size,
                              hipStream_t stream) {
    const float* offset = (const float*)d_in[0];   // [4,18,512,512]
    const float* flow   = (const float*)d_in[1];   // [4,8,512,512]
    float* partial = (float*)d_ws;                 // NPART floats (64 KB), fully rewritten
    float* out     = (float*)d_out;                // 1 float

    pos_loss_main<<<GRID1, BLK, 0, stream>>>(offset, flow, partial);
    pos_loss_reduce<<<1, RBLK, 0, stream>>>(partial, out);
}

// Round 11
// 26.685 us; speedup vs baseline: 2.6612x; 1.2469x over previous
//
#include <hip/hip_runtime.h>

// PositionLossVal: offset [4,18,512,512] f32, optical_flow [4,8,512,512] f32 -> scalar f32.
// Per pixel: x=off[i], y=off[i+9] (i<9); u=flow[j], v=flow[j+1] (j<4).
// md = inside ? perp : min(d1,d2); min over j, mean over i, sum over b,h,w, /(h*w).
// min over j in squared domain -> 1 sqrt per (pixel,i).
// inside: x0*(x0-u)<=0, x0 = u*(x^2+v*y)/uu  <=>  w*(w-uu)<=0 with w = x^2+v*y.
//
// Ledger: R5 same-address atomic tail +60us. PPT=4 => 180 VGPR (2 waves/SIMD), dead.
// __launch_bounds__(256,N) min-waves arg makes hipcc target (512/N)/2 VGPRs and
// force-spill (R4/R8/R9: 100-160MB scratch) — never pass it. R10 global_load_lds
// tile: stage->vmcnt(0)->compute serialization costs +6us vs VGPR-held loads.
// Best: R3 (PPT=2, 26.7us). R11 = R3 body, UNCAPPED: all 23 float2 loads issued
// up-front (~90-reg live set, no forced batching), 4-6 waves/SIMD.

#define HW_BITS 18
#define HW_ (1 << HW_BITS)          // 512*512
#define NOFF 9
#define NFLOW 4
#define NPIX (4 * HW_)              // 1,048,576 pixels
#define PPT 2                       // pixels per thread (float2 loads)
#define BLK 256
#define GRID1 (NPIX / PPT / BLK)    // 2048 blocks
#define NPART (GRID1 * (BLK / 64))  // 8192 wave partials (32 KB)
#define RBLK 1024

__global__ __launch_bounds__(BLK)   // block size only — min-waves arg is poison (ledger)
void pos_loss_main(const float* __restrict__ off, const float* __restrict__ flow,
                   float* __restrict__ partial)
{
    const int t  = blockIdx.x * BLK + threadIdx.x;
    const int g  = t * PPT;                          // 2 consecutive pixels, same image
    const int b  = g >> HW_BITS;
    const int hw = g & (HW_ - 1);
    const float* offb = off  + ((size_t)b * (2 * NOFF)) * HW_ + hw;
    const float* flb  = flow + ((size_t)b * 8) * HW_ + hw;

    // ALL 23 float2 loads issued before any use: ~46 load-dest regs, uncapped VGPR
    // lets the scheduler keep them all in flight (this was impossible at 64 VGPR).
    float2 f2[NFLOW + 1];
#pragma unroll
    for (int j = 0; j <= NFLOW; ++j)
        f2[j] = *reinterpret_cast<const float2*>(flb + (size_t)j * HW_);
    float2 xs2[NOFF], ys2[NOFF];
#pragma unroll
    for (int i = 0; i < NOFF; ++i) {
        xs2[i] = *reinterpret_cast<const float2*>(offb + (size_t)i * HW_);
        ys2[i] = *reinterpret_cast<const float2*>(offb + (size_t)(i + NOFF) * HW_);
    }

    // Per-(px,j) invariants: uu = u^2+v^2, r = 1/uu.
    float uu_[PPT][NFLOW], r_[PPT][NFLOW];
#pragma unroll
    for (int j = 0; j < NFLOW; ++j) {
        const float up[PPT] = {f2[j].x, f2[j].y};
        const float vp[PPT] = {f2[j + 1].x, f2[j + 1].y};
#pragma unroll
        for (int p = 0; p < PPT; ++p) {
            const float uu = fmaf(up[p], up[p], vp[p] * vp[p]);
            uu_[p][j] = uu;
            r_[p][j]  = __builtin_amdgcn_rcpf(uu);
        }
    }

    float acc = 0.f;
#pragma unroll
    for (int i = 0; i < NOFF; ++i) {
        const float xp[PPT] = {xs2[i].x, xs2[i].y};
        const float yp[PPT] = {ys2[i].x, ys2[i].y};
#pragma unroll
        for (int p = 0; p < PPT; ++p) {
            const float x  = xp[p], y = yp[p];
            const float x2 = x * x;
            const float d1sq = fmaf(y, y, x2);
            float m2 = 1e30f;
#pragma unroll
            for (int j = 0; j < NFLOW; ++j) {
                const float u = (p == 0) ? f2[j].x : f2[j].y;
                const float v = (p == 0) ? f2[j + 1].x : f2[j + 1].y;
                const float w   = fmaf(v, y, x2);                 // x^2 + v*y
                const float ins = w * (w - uu_[p][j]);            // sign == x0*(x0-u)
                const float tt  = fmaf(v, x, -(u * y));           // v*x - u*y
                const float p2  = (tt * tt) * r_[p][j];
                const float dx = x - u, dy = y - v;
                const float d2sq = fmaf(dy, dy, dx * dx);
                const float e2  = fminf(d1sq, d2sq);
                const float md2 = (ins <= 0.f) ? p2 : e2;
                m2 = fminf(m2, md2);
            }
            acc += __builtin_amdgcn_sqrtf(m2);
        }
    }

    // Per-wave shuffle reduce; no barrier — waves retire independently.
#pragma unroll
    for (int o = 32; o > 0; o >>= 1) acc += __shfl_down(acc, o, 64);
    if ((threadIdx.x & 63) == 0)
        partial[blockIdx.x * (BLK / 64) + (threadIdx.x >> 6)] = acc;
}

__global__ __launch_bounds__(RBLK)
void pos_loss_reduce(const float* __restrict__ partial, float* __restrict__ out)
{
    float s = 0.f;
#pragma unroll
    for (int k = 0; k < NPART / RBLK; ++k)          // 8 coalesced loads
        s += partial[k * RBLK + (int)threadIdx.x];
#pragma unroll
    for (int o = 32; o > 0; o >>= 1) s += __shfl_down(s, o, 64);
    __shared__ float sm[RBLK / 64];                 // 16 wave sums
    const int lane = threadIdx.x & 63, wid = threadIdx.x >> 6;
    if (lane == 0) sm[wid] = s;
    __syncthreads();
    if (wid == 0) {
        float v = (lane < RBLK / 64) ? sm[lane] : 0.f;
#pragma unroll
        for (int o = 8; o > 0; o >>= 1) v += __shfl_down(v, o, 64);
        if (lane == 0)
            out[0] = v * (1.0f / (9.0f * (float)HW_));
    }
}

extern "C" void kernel_launch(void* const* d_in, const int* in_sizes, int n_in,
                              void* d_out, int out_size, void* d_ws, size_t ws_size,
                              hipStream_t stream) {
    const float* offset = (const float*)d_in[0];   // [4,18,512,512]
    const float* flow   = (const float*)d_in[1];   // [4,8,512,512]
    float* partial = (float*)d_ws;                 // NPART floats (32 KB), fully rewritten
    float* out     = (float*)d_out;                // 1 float

    pos_loss_main<<<GRID1, BLK, 0, stream>>>(offset, flow, partial);
    pos_loss_reduce<<<1, RBLK, 0, stream>>>(partial, out);
}

// Round 12
// 25.117 us; speedup vs baseline: 2.8274x; 1.0624x over previous
//
#include <hip/hip_runtime.h>

// PositionLossVal: offset [4,18,512,512] f32, optical_flow [4,8,512,512] f32 -> scalar f32.
// Per pixel: x=off[i], y=off[i+9] (i<9); u=flow[j], v=flow[j+1] (j<4).
// md = inside ? perp : min(d1,d2); min over j, mean over i, sum over b,h,w, /(h*w).
// min over j in squared domain -> 1 sqrt per (pixel,i).
// inside: x0*(x0-u)<=0, x0 = u*(x^2+v*y)/uu  <=>  w*(w-uu)<=0 with w = x^2+v*y.
//
// Ledger: R5 same-address atomic tail +60us (device-scope RMWs serialize at the
// cross-XCD coherence point). PPT=4 => 180 VGPR, 2 waves/SIMD — dead (R1/R7).
// __launch_bounds__(256,N) min-waves arg => hipcc targets (512/N)/2 VGPRs and
// force-spills 100-160MB scratch (R4/R8/R9) — never pass it. R10 global_load_lds
// tile: stage->drain->compute serialization +6us vs VGPR-held. R2/R3/R6/R11 all
// converge 26.7-27.1us: occupancy/bytes-in-flight/reduction-shape all null.
// Across 5 profiled variants VALUBusy*dur ~= 15-16us invariant => likely VALU-bound.
// R12: express the PPT=2 pixel pair as ext_vector float2 so the backend can form
// VOP3P packed-f32 (v_pk_fma_f32 etc, gfx90a+): mul/fma/sub pack 2-for-1,
// cmp/select/min stay scalar. Same f32 semantics as R11.

#define HW_BITS 18
#define HW_ (1 << HW_BITS)          // 512*512
#define NOFF 9
#define NFLOW 4
#define NPIX (4 * HW_)              // 1,048,576 pixels
#define PPT 2                       // pixel pair lives in the two halves of a v2f
#define BLK 256
#define GRID1 (NPIX / PPT / BLK)    // 2048 blocks
#define NPART (GRID1 * (BLK / 64))  // 8192 wave partials (32 KB)
#define RBLK 1024

typedef float v2f __attribute__((ext_vector_type(2)));

__global__ __launch_bounds__(BLK)   // block size only — min-waves arg is poison (ledger)
void pos_loss_main(const float* __restrict__ off, const float* __restrict__ flow,
                   float* __restrict__ partial)
{
    const int t  = blockIdx.x * BLK + threadIdx.x;
    const int g  = t * PPT;                          // 2 consecutive pixels, same image
    const int b  = g >> HW_BITS;
    const int hw = g & (HW_ - 1);
    const float* offb = off  + ((size_t)b * (2 * NOFF)) * HW_ + hw;
    const float* flb  = flow + ((size_t)b * 8) * HW_ + hw;

    // All 23 vec2 loads issued before first use (R11 structure).
    v2f f2[NFLOW + 1];
#pragma unroll
    for (int j = 0; j <= NFLOW; ++j)
        f2[j] = *reinterpret_cast<const v2f*>(flb + (size_t)j * HW_);
    v2f xs2[NOFF], ys2[NOFF];
#pragma unroll
    for (int i = 0; i < NOFF; ++i) {
        xs2[i] = *reinterpret_cast<const v2f*>(offb + (size_t)i * HW_);
        ys2[i] = *reinterpret_cast<const v2f*>(offb + (size_t)(i + NOFF) * HW_);
    }

    // Per-j invariants on the pixel pair: uu = u^2+v^2, r = 1/uu.
    v2f uu_[NFLOW], r_[NFLOW];
#pragma unroll
    for (int j = 0; j < NFLOW; ++j) {
        const v2f u = f2[j], v = f2[j + 1];
        const v2f uu = u * u + v * v;               // packs: pk_mul + pk_fma
        uu_[j] = uu;
        r_[j].x = __builtin_amdgcn_rcpf(uu.x);      // trans ops are scalar anyway
        r_[j].y = __builtin_amdgcn_rcpf(uu.y);
    }

    v2f acc = {0.f, 0.f};
#pragma unroll
    for (int i = 0; i < NOFF; ++i) {
        const v2f x  = xs2[i], y = ys2[i];
        const v2f x2 = x * x;
        const v2f d1sq = y * y + x2;
        v2f m2 = {1e30f, 1e30f};
#pragma unroll
        for (int j = 0; j < NFLOW; ++j) {
            const v2f u = f2[j], v = f2[j + 1];
            // Packed portion (mul/fma/sub all eligible for v_pk_*_f32):
            const v2f w    = v * y + x2;            // x^2 + v*y
            const v2f ins  = w * (w - uu_[j]);      // sign == x0*(x0-u)
            const v2f tt   = v * x - u * y;
            const v2f p2   = tt * tt * r_[j];
            const v2f dx   = x - u, dy = y - v;
            const v2f d2sq = dy * dy + dx * dx;
            // Scalar tail per pixel (cmp/select/min have no packed form):
            m2.x = fminf(m2.x, (ins.x <= 0.f) ? p2.x : fminf(d1sq.x, d2sq.x));
            m2.y = fminf(m2.y, (ins.y <= 0.f) ? p2.y : fminf(d1sq.y, d2sq.y));
        }
        acc.x += __builtin_amdgcn_sqrtf(m2.x);
        acc.y += __builtin_amdgcn_sqrtf(m2.y);
    }
    float a = acc.x + acc.y;

    // Per-wave shuffle reduce; no barrier — waves retire independently.
#pragma unroll
    for (int o = 32; o > 0; o >>= 1) a += __shfl_down(a, o, 64);
    if ((threadIdx.x & 63) == 0)
        partial[blockIdx.x * (BLK / 64) + (threadIdx.x >> 6)] = a;
}

__global__ __launch_bounds__(RBLK)
void pos_loss_reduce(const float* __restrict__ partial, float* __restrict__ out)
{
    float s = 0.f;
#pragma unroll
    for (int k = 0; k < NPART / RBLK; ++k)          // 8 coalesced loads
        s += partial[k * RBLK + (int)threadIdx.x];
#pragma unroll
    for (int o = 32; o > 0; o >>= 1) s += __shfl_down(s, o, 64);
    __shared__ float sm[RBLK / 64];                 // 16 wave sums
    const int lane = threadIdx.x & 63, wid = threadIdx.x >> 6;
    if (lane == 0) sm[wid] = s;
    __syncthreads();
    if (wid == 0) {
        float v = (lane < RBLK / 64) ? sm[lane] : 0.f;
#pragma unroll
        for (int o = 8; o > 0; o >>= 1) v += __shfl_down(v, o, 64);
        if (lane == 0)
            out[0] = v * (1.0f / (9.0f * (float)HW_));
    }
}

extern "C" void kernel_launch(void* const* d_in, const int* in_sizes, int n_in,
                              void* d_out, int out_size, void* d_ws, size_t ws_size,
                              hipStream_t stream) {
    const float* offset = (const float*)d_in[0];   // [4,18,512,512]
    const float* flow   = (const float*)d_in[1];   // [4,8,512,512]
    float* partial = (float*)d_ws;                 // NPART floats (32 KB), fully rewritten
    float* out     = (float*)d_out;                // 1 float

    pos_loss_main<<<GRID1, BLK, 0, stream>>>(offset, flow, partial);
    pos_loss_reduce<<<1, RBLK, 0, stream>>>(partial, out);
}

// Round 13
// 24.782 us; speedup vs baseline: 2.8656x; 1.0135x over previous
//
#include <hip/hip_runtime.h>

// PositionLossVal: offset [4,18,512,512] f32, optical_flow [4,8,512,512] f32 -> scalar f32.
// Per pixel: x=off[i], y=off[i+9] (i<9); u=flow[j], v=flow[j+1] (j<4).
// md = inside ? perp : min(d1,d2); min over j, mean over i, sum over b,h,w, /(h*w).
//
// Ledger: R5 same-address atomic tail +60us. PPT=4 => 180 VGPR, dead (R1/R7).
// __launch_bounds__ min-waves arg => allocator targets half the implied VGPR cap and
// force-spills 100-160MB (R4/R8/R9) — never pass it. R10 global_load_lds tile:
// stage->drain serialization +6us. R2/R3/R6/R11 structure-invariant 26.7-27.1us.
// R12 packed-f32 (VOP3P v_pk_*): 25.1us — VALU issue count is live.
// R13 algebraic trims (exact math, new fp contraction):
//   proj = x*u+y*v shared:  p2 = d1sq - proj^2*r   (Lagrange identity)
//                           d2sq = d1sq + uu - 2*proj
//   packed/(i,j): 11 -> 9.  Scalar tail via perp<=d2 identity:
//   m2 = min3(m2, d2sq, inside ? p2 : d1sq)  (4 -> 3 scalar/px).
//   Clamp m2>=0 per i (fp cancellation can give ~ulp-negative p2/d2sq -> sqrt NaN).

#define HW_BITS 18
#define HW_ (1 << HW_BITS)          // 512*512
#define NOFF 9
#define NFLOW 4
#define NPIX (4 * HW_)              // 1,048,576 pixels
#define PPT 2                       // pixel pair in the two halves of a v2f
#define BLK 256
#define GRID1 (NPIX / PPT / BLK)    // 2048 blocks
#define NPART (GRID1 * (BLK / 64))  // 8192 wave partials (32 KB)
#define RBLK 1024

typedef float v2f __attribute__((ext_vector_type(2)));

__global__ __launch_bounds__(BLK)   // block size only — min-waves arg is poison (ledger)
void pos_loss_main(const float* __restrict__ off, const float* __restrict__ flow,
                   float* __restrict__ partial)
{
    const int t  = blockIdx.x * BLK + threadIdx.x;
    const int g  = t * PPT;                          // 2 consecutive pixels, same image
    const int b  = g >> HW_BITS;
    const int hw = g & (HW_ - 1);
    const float* offb = off  + ((size_t)b * (2 * NOFF)) * HW_ + hw;
    const float* flb  = flow + ((size_t)b * 8) * HW_ + hw;

    // All 23 vec2 loads issued before first use.
    v2f f2[NFLOW + 1];
#pragma unroll
    for (int j = 0; j <= NFLOW; ++j)
        f2[j] = *reinterpret_cast<const v2f*>(flb + (size_t)j * HW_);
    v2f xs2[NOFF], ys2[NOFF];
#pragma unroll
    for (int i = 0; i < NOFF; ++i) {
        xs2[i] = *reinterpret_cast<const v2f*>(offb + (size_t)i * HW_);
        ys2[i] = *reinterpret_cast<const v2f*>(offb + (size_t)(i + NOFF) * HW_);
    }

    // Per-j invariants: uu = u^2+v^2, r = 1/uu.
    v2f uu_[NFLOW], r_[NFLOW];
#pragma unroll
    for (int j = 0; j < NFLOW; ++j) {
        const v2f u = f2[j], v = f2[j + 1];
        const v2f uu = u * u + v * v;
        uu_[j] = uu;
        r_[j].x = __builtin_amdgcn_rcpf(uu.x);
        r_[j].y = __builtin_amdgcn_rcpf(uu.y);
    }

    v2f acc = {0.f, 0.f};
#pragma unroll
    for (int i = 0; i < NOFF; ++i) {
        const v2f x  = xs2[i], y = ys2[i];
        const v2f x2 = x * x;
        const v2f d1sq = y * y + x2;
        v2f m2 = {1e30f, 1e30f};
#pragma unroll
        for (int j = 0; j < NFLOW; ++j) {
            const v2f u = f2[j], v = f2[j + 1];
            const v2f uu = uu_[j];
            // Packed portion (9 v_pk_* ops):
            const v2f proj = x * u + y * v;         // mul + fma
            const v2f p2   = d1sq - (proj * proj) * r_[j];   // mul + fma  (Lagrange)
            const v2f d1uu = d1sq + uu;
            const v2f d2sq = d1uu - 2.0f * proj;    // fma(-2, proj, d1uu)
            const v2f w    = v * y + x2;            // fma
            const v2f ins  = w * (w - uu);          // sub + mul (sign == x0*(x0-u))
            // Scalar tail (3 ops/px: cmp+cndmask, then min3 chain):
            const float selx = (ins.x <= 0.f) ? p2.x : d1sq.x;
            const float sely = (ins.y <= 0.f) ? p2.y : d1sq.y;
            m2.x = fminf(fminf(m2.x, d2sq.x), selx);
            m2.y = fminf(fminf(m2.y, d2sq.y), sely);
        }
        acc.x += __builtin_amdgcn_sqrtf(fmaxf(m2.x, 0.f));
        acc.y += __builtin_amdgcn_sqrtf(fmaxf(m2.y, 0.f));
    }
    float a = acc.x + acc.y;

    // Per-wave shuffle reduce; no barrier — waves retire independently.
#pragma unroll
    for (int o = 32; o > 0; o >>= 1) a += __shfl_down(a, o, 64);
    if ((threadIdx.x & 63) == 0)
        partial[blockIdx.x * (BLK / 64) + (threadIdx.x >> 6)] = a;
}

__global__ __launch_bounds__(RBLK)
void pos_loss_reduce(const float* __restrict__ partial, float* __restrict__ out)
{
    float s = 0.f;
#pragma unroll
    for (int k = 0; k < NPART / RBLK; ++k)          // 8 coalesced loads
        s += partial[k * RBLK + (int)threadIdx.x];
#pragma unroll
    for (int o = 32; o > 0; o >>= 1) s += __shfl_down(s, o, 64);
    __shared__ float sm[RBLK / 64];                 // 16 wave sums
    const int lane = threadIdx.x & 63, wid = threadIdx.x >> 6;
    if (lane == 0) sm[wid] = s;
    __syncthreads();
    if (wid == 0) {
        float v = (lane < RBLK / 64) ? sm[lane] : 0.f;
#pragma unroll
        for (int o = 8; o > 0; o >>= 1) v += __shfl_down(v, o, 64);
        if (lane == 0)
            out[0] = v * (1.0f / (9.0f * (float)HW_));
    }
}

extern "C" void kernel_launch(void* const* d_in, const int* in_sizes, int n_in,
                              void* d_out, int out_size, void* d_ws, size_t ws_size,
                              hipStream_t stream) {
    const float* offset = (const float*)d_in[0];   // [4,18,512,512]
    const float* flow   = (const float*)d_in[1];   // [4,8,512,512]
    float* partial = (float*)d_ws;                 // NPART floats (32 KB), fully rewritten
    float* out     = (float*)d_out;                // 1 float

    pos_loss_main<<<GRID1, BLK, 0, stream>>>(offset, flow, partial);
    pos_loss_reduce<<<1, RBLK, 0, stream>>>(partial, out);
}